// Round 4
// baseline (1293.755 us; speedup 1.0000x reference)
//
#include <hip/hip_runtime.h>

// Single-pass stable stream compaction, decoupled lookback — AGG-only waiting.
// y[:count] = x[x>0] in original order, y[count:n] = 0, y[out_size-1] = (float)count.
//
// R1 lesson (measured): waiting on inclusive-prefix flags serializes 16384
// blocks at ~119 ns/hop (1956 us). Fix: blocks wait ONLY on aggregate flags
// (which depend on nothing cross-block), and each block sums ALL predecessor
// aggregates itself, distributed over 256 threads (<=64 dependent flag loads
// for the last block, overlapped across ~2048 resident blocks).
//
// Ticket assignment (1 atomicAdd/block) makes virtual block order = execution
// start order, so predecessors of any virtual block are resident-or-retired:
// no deadlock regardless of dispatch order/occupancy.
//
// Traffic: read x once (256 MB) + write y once (257 MB) + flag noise.

#define BLOCK 256
#define VPT 16               // elems per thread (contiguous)
#define CHUNK (BLOCK * VPT)  // 4096
#define FLAG_VALID 0x80000000u
#define FLAG_MASK  0x7FFFFFFFu

// Zero flags[0..numBlocks-1] and the ticket counter at flags[numBlocks].
__global__ void k_init(unsigned int* __restrict__ flags, int numBlocks) {
    const int i = blockIdx.x * BLOCK + threadIdx.x;
    if (i <= numBlocks) flags[i] = 0u;
}

__global__ void __launch_bounds__(BLOCK)
k_compact(const float* __restrict__ x, int n, int numBlocks, int out_size,
          unsigned int* __restrict__ flags, float* __restrict__ y) {
    __shared__ __align__(16) float vals[CHUNK + 4];  // +pad (<=3) for aligned output
    __shared__ int lds[12];          // [0..3] wave totals, [4..7] scan tails, [8..11] lookback sums
    __shared__ unsigned int s_bid;

    const int tid  = threadIdx.x;
    const int lane = tid & 63;
    const int wave = tid >> 6;

    if (tid == 0) s_bid = atomicAdd(&flags[numBlocks], 1u);  // ticket
    __syncthreads();
    const int b = (int)s_bid;
    const int chunkBase = b * CHUNK;
    const long long tbase = (long long)chunkBase + tid * VPT;

    float v[VPT];
    if ((long long)chunkBase + CHUNK <= n) {
#pragma unroll
        for (int k = 0; k < 4; ++k) {
            const float4 f = *reinterpret_cast<const float4*>(x + tbase + 4 * k);
            v[4 * k + 0] = f.x; v[4 * k + 1] = f.y; v[4 * k + 2] = f.z; v[4 * k + 3] = f.w;
        }
    } else {
#pragma unroll
        for (int j = 0; j < VPT; ++j)
            v[j] = (tbase + j < n) ? x[tbase + j] : 0.f;
    }

    int c = 0;
#pragma unroll
    for (int j = 0; j < VPT; ++j) c += (v[j] > 0.f);

    // Quick block total -> publish aggregate ASAP (tightens same-generation spins).
    int t64 = c;
#pragma unroll
    for (int off = 32; off > 0; off >>= 1) t64 += __shfl_down(t64, off, 64);
    if (lane == 0) lds[wave] = t64;
    __syncthreads();
    const int total = lds[0] + lds[1] + lds[2] + lds[3];
    if (tid == 0) {
        __hip_atomic_store(&flags[b], FLAG_VALID | (unsigned)total,
                           __ATOMIC_RELEASE, __HIP_MEMORY_SCOPE_AGENT);
    }

    // Exclusive rank within block.
    int incl = c;
#pragma unroll
    for (int off = 1; off < 64; off <<= 1) {
        const int u = __shfl_up(incl, off, 64);
        if (lane >= off) incl += u;
    }
    if (lane == 63) lds[4 + wave] = incl;
    __syncthreads();
    int waveEx = 0;
#pragma unroll
    for (int w = 0; w < 4; ++w) waveEx += (w < wave) ? lds[4 + w] : 0;
    int r = waveEx + incl - c;

    // Decoupled lookback, AGG-only: thread t sums flags[b-1-t], [b-1-t-256], ...
    int sum = 0;
    for (int idx = b - 1 - tid; idx >= 0; idx -= BLOCK) {
        unsigned int f = __hip_atomic_load(&flags[idx], __ATOMIC_RELAXED,
                                           __HIP_MEMORY_SCOPE_AGENT);
        while (!(f & FLAG_VALID)) {
            __builtin_amdgcn_s_sleep(2);
            f = __hip_atomic_load(&flags[idx], __ATOMIC_RELAXED,
                                  __HIP_MEMORY_SCOPE_AGENT);
        }
        sum += (int)(f & FLAG_MASK);
    }
#pragma unroll
    for (int off = 32; off > 0; off >>= 1) sum += __shfl_down(sum, off, 64);
    if (lane == 0) lds[8 + wave] = sum;
    __syncthreads();
    const int excl = lds[8] + lds[9] + lds[10] + lds[11];

    // Stage positives shifted by pad so the output body is 16B-aligned.
    const int pad = excl & 3;
    r += pad;
#pragma unroll
    for (int j = 0; j < VPT; ++j) {
        if (v[j] > 0.f) vals[r++] = v[j];
    }
    __syncthreads();

    // Vectorized store of positives: vals[k] <-> y[yb + k], yb = excl - pad.
    const int m = pad + total;
    const long long yb = (long long)excl - pad;
    const int nq = (m + 3) >> 2;
    for (int t = tid; t < nq; t += BLOCK) {
        const int k0 = 4 * t;
        if (k0 >= pad && k0 + 4 <= m) {
            *reinterpret_cast<float4*>(y + yb + k0) =
                *reinterpret_cast<const float4*>(&vals[k0]);
        } else {
            const int ks = (k0 < pad) ? pad : k0;
            const int ke = (k0 + 4 < m) ? k0 + 4 : m;
            for (int k = ks; k < ke; ++k) y[yb + k] = vals[k];
        }
    }

    // Fused zerofill: this block's zeros tile a slice of [count, n) from the
    // top down; regions are disjoint and cover [count, n) exactly.
    const int rem   = n - chunkBase;
    const int elems = rem < CHUNK ? rem : CHUNK;
    const int z     = elems - total;
    const long long zhi = (long long)n - (chunkBase - excl);
    const long long zlo = zhi - z;
    const long long za  = (zlo + 3) & ~3LL;    // first aligned quad start
    const long long zb  = zhi & ~3LL;          // last aligned quad end
    if (za >= zb) {
        for (long long j = zlo + tid; j < zhi; j += BLOCK) y[j] = 0.f;
    } else {
        if (tid < (int)(za - zlo)) y[zlo + tid] = 0.f;                     // head (<=3)
        if (tid >= 4 && tid - 4 < (int)(zhi - zb)) y[zb + tid - 4] = 0.f;  // tail (<=3)
        const int zq = (int)((zb - za) >> 2);
        const float4 zero = make_float4(0.f, 0.f, 0.f, 0.f);
        for (int t = tid; t < zq; t += BLOCK) {
            *reinterpret_cast<float4*>(y + za + 4 * t) = zero;
        }
    }

    if (b == numBlocks - 1 && tid == 0) {
        y[out_size - 1] = (float)(excl + total);
    }
}

extern "C" void kernel_launch(void* const* d_in, const int* in_sizes, int n_in,
                              void* d_out, int out_size, void* d_ws, size_t ws_size,
                              hipStream_t stream) {
    const float* x = (const float*)d_in[0];
    float* y = (float*)d_out;
    const int n = in_sizes[0];

    unsigned int* flags = (unsigned int*)d_ws;      // numBlocks flags + 1 ticket
    const int numBlocks = (n + CHUNK - 1) / CHUNK;  // 16384 for N=64M

    const int initBlocks = (numBlocks + 1 + BLOCK - 1) / BLOCK;
    k_init<<<initBlocks, BLOCK, 0, stream>>>(flags, numBlocks);
    k_compact<<<numBlocks, BLOCK, 0, stream>>>(x, n, numBlocks, out_size, flags, y);
}